// Round 8
// baseline (2921.246 us; speedup 1.0000x reference)
//
#include <hip/hip_runtime.h>
#include <hip/hip_bf16.h>

typedef float f32x4 __attribute__((ext_vector_type(4)));
typedef unsigned int u32;
typedef u32 u32x2 __attribute__((ext_vector_type(2)));
typedef u32 u32x4 __attribute__((ext_vector_type(4)));

#define SD 8192      // S*D
#define NROWS 8192   // B*N
#define NN 4096      // N
#define DD 2048      // D

__device__ __forceinline__ u32 bfr(float f) {   // f32 -> bf16 bits, RNE
    u32 u = __float_as_uint(f);
    return (u + 0x7fffu + ((u >> 16) & 1u)) >> 16;
}
__device__ __forceinline__ float blo(u32 u) { return __uint_as_float(u << 16); }
__device__ __forceinline__ float bhi(u32 u) { return __uint_as_float(u & 0xffff0000u); }

// K0: Wbf[k][j] = bf16( w[j][k] * (gamma[j]+1) ), k 0..23 (20 alpha, 4 beta)
__global__ void k0_prep(const float* __restrict__ gamma,
                        const float* __restrict__ daf,
                        const float* __restrict__ dbf,
                        __hip_bfloat16* __restrict__ Wbf) {
    int idx = blockIdx.x * 256 + threadIdx.x;
    if (idx >= 24 * SD) return;
    int k = idx >> 13;
    int j = idx & (SD - 1);
    float g = gamma[j] + 1.0f;
    float w = (k < 20) ? daf[j * 20 + k] : dbf[j * 4 + (k - 20)];
    ((unsigned short*)Wbf)[(size_t)k * SD + j] = (unsigned short)bfr(w * g);
}

// KF: fused. Block = 4 (b,n)-rows, 512 threads (8 waves), 2 blocks/CU.
// P1: stage rows f32->reg (exact ssq) ->bf16 LDS (64 KiB).
// P2: projections: wave (kg=w>>1 owns 6 k, jg=w&1 owns j-half) from bf16 LDS
//     data x bf16 global weights (L2-resident, each element once per block).
// P3: wave 0: sinkhorn (20 it) + coeff for the 4 rows.
// P4: mix from bf16 LDS, nontemporal f32x4 stores.
__global__ __launch_bounds__(512, 4) void kf(const float* __restrict__ res,
                                             const __hip_bfloat16* __restrict__ Wbf,
                                             const float* __restrict__ sa,
                                             const float* __restrict__ sb,
                                             const float* __restrict__ pbs,
                                             const float* __restrict__ rsc,
                                             const float* __restrict__ hps,
                                             float* __restrict__ out) {
    __shared__ u32 dT[4][4096];        // packed bf16x2; row r, pair jp (j=2*jp); 64 KiB
    __shared__ float ssqw[8];
    __shared__ float rsum[2][4][24];   // [jg][row][k]
    __shared__ float coefS[4][16];

    const int tid  = threadIdx.x;
    const int wv   = tid >> 6;
    const int lane = tid & 63;
    const int row0 = blockIdx.x * 4;
    const int b    = row0 >> 12;
    const int n0   = row0 & (NN - 1);
    const int r    = tid >> 7;          // staging/mix row 0..3
    const int rem  = tid & 127;

    // ---------- P1: stage 4 rows, exact ssq, pack bf16 ----------
    const float* rowbase = res + ((size_t)(b * 4) * NN + (n0 + r)) * DD;
    float ssq = 0.f;
#pragma unroll
    for (int h = 0; h < 2; ++h) {
        f32x4 v[8];
#pragma unroll
        for (int i = 0; i < 8; ++i) {
            const int q  = h * 8 + i;
            const int j0 = (rem + 128 * q) * 4;
            const int s  = j0 >> 11, d = j0 & 2047;
            v[i] = *(const f32x4*)(rowbase + (size_t)s * NN * DD + d);
        }
#pragma unroll
        for (int i = 0; i < 8; ++i) {
            ssq += v[i].x * v[i].x + v[i].y * v[i].y + v[i].z * v[i].z + v[i].w * v[i].w;
            u32 lo = (bfr(v[i].y) << 16) | bfr(v[i].x);
            u32 hi = (bfr(v[i].w) << 16) | bfr(v[i].z);
            const int jp = (rem + 128 * (h * 8 + i)) * 2;
            *(u32x2*)&dT[r][jp] = (u32x2){lo, hi};
        }
    }
    // wave covers a single row -> butterfly then one slot per wave
    ssq += __shfl_xor(ssq, 1);  ssq += __shfl_xor(ssq, 2);
    ssq += __shfl_xor(ssq, 4);  ssq += __shfl_xor(ssq, 8);
    ssq += __shfl_xor(ssq, 16); ssq += __shfl_xor(ssq, 32);
    if (lane == 0) ssqw[wv] = ssq;
    __syncthreads();

    // ---------- P2: projections ----------
    {
        const int kg = wv >> 1, jg = wv & 1;
        const int k0 = kg * 6;
        float acc[4][6];
#pragma unroll
        for (int rr = 0; rr < 4; ++rr)
#pragma unroll
            for (int kk = 0; kk < 6; ++kk) acc[rr][kk] = 0.f;

        const unsigned short* wb = (const unsigned short*)Wbf + (size_t)k0 * SD + jg * 4096 + lane * 8;
#pragma unroll
        for (int i = 0; i < 8; ++i) {
            const int jp0 = jg * 2048 + i * 256 + lane * 4;
            u32x4 dr[4];
#pragma unroll
            for (int rr = 0; rr < 4; ++rr) dr[rr] = *(const u32x4*)&dT[rr][jp0];
            float df[4][8];
#pragma unroll
            for (int rr = 0; rr < 4; ++rr)
#pragma unroll
                for (int p = 0; p < 4; ++p) {
                    df[rr][2 * p]     = blo(dr[rr][p]);
                    df[rr][2 * p + 1] = bhi(dr[rr][p]);
                }
#pragma unroll
            for (int kk = 0; kk < 6; ++kk) {
                const u32x4 wq = *(const u32x4*)(wb + (size_t)kk * SD + i * 512);
#pragma unroll
                for (int p = 0; p < 4; ++p) {
                    const float wlo = blo(wq[p]), whi = bhi(wq[p]);
#pragma unroll
                    for (int rr = 0; rr < 4; ++rr) {
                        acc[rr][kk] += df[rr][2 * p] * wlo;
                        acc[rr][kk] += df[rr][2 * p + 1] * whi;
                    }
                }
            }
        }
#pragma unroll
        for (int rr = 0; rr < 4; ++rr)
#pragma unroll
            for (int kk = 0; kk < 6; ++kk) {
                float v = acc[rr][kk];
                v += __shfl_xor(v, 1);  v += __shfl_xor(v, 2);
                v += __shfl_xor(v, 4);  v += __shfl_xor(v, 8);
                v += __shfl_xor(v, 16); v += __shfl_xor(v, 32);
                if (lane == 0) rsum[jg][rr][k0 + kk] = v;
            }
    }
    __syncthreads();

    // ---------- P3: sinkhorn + coeff (wave 0; 4 rows x 16 lanes) ----------
    if (wv == 0) {
        const int rr = lane >> 4, l = lane & 15, s = l >> 2, t = l & 3;
        const float ssqr  = ssqw[2 * rr] + ssqw[2 * rr + 1];
        const float scale = 90.50966799187809f / fmaxf(sqrtf(ssqr), 1e-12f);
        const float P  = rsum[0][rr][s * 5 + t + 1] + rsum[1][rr][s * 5 + t + 1];
        const float P0 = rsum[0][rr][s * 5]         + rsum[1][rr][s * 5];
        const float Pb = rsum[0][rr][20 + t]        + rsum[1][rr][20 + t];
        float la = scale * P * rsc[0] + sa[s * 5 + t + 1];
        const float a0 = scale * P0 * pbs[0] + sa[s * 5];
        const float ap = 1.f / (1.f + __expf(-a0));
        const float bt = 2.f / (1.f + __expf(-(scale * Pb * hps[0] + sb[t])));
#pragma unroll
        for (int it = 0; it < 20; ++it) {
            float m = fmaxf(la, __shfl_xor(la, 4));
            m = fmaxf(m, __shfl_xor(m, 8));
            float e = __expf(la - m);
            e += __shfl_xor(e, 4);
            e += __shfl_xor(e, 8);
            la -= m + __logf(e);
            m = fmaxf(la, __shfl_xor(la, 1));
            m = fmaxf(m, __shfl_xor(m, 2));
            e = __expf(la - m);
            e += __shfl_xor(e, 1);
            e += __shfl_xor(e, 2);
            la -= m + __logf(e);
        }
        coefS[rr][t * 4 + s] = ap * bt + __expf(la);
    }
    __syncthreads();

    // ---------- P4: mix + store ----------
    float cf[16];
#pragma unroll
    for (int i = 0; i < 16; ++i) cf[i] = coefS[r][i];
    float* ob = out + ((size_t)(b * 4) * NN + (n0 + r)) * DD;
#pragma unroll
    for (int qq = 0; qq < 4; ++qq) {
        const int d0 = (rem + 128 * qq) * 4;
        float dv[4][4];
#pragma unroll
        for (int s = 0; s < 4; ++s) {
            u32x2 u = *(const u32x2*)&dT[r][s * 1024 + d0 / 2];
            dv[s][0] = blo(u[0]); dv[s][1] = bhi(u[0]);
            dv[s][2] = blo(u[1]); dv[s][3] = bhi(u[1]);
        }
#pragma unroll
        for (int t = 0; t < 4; ++t) {
            f32x4 o;
            o.x = cf[t * 4 + 0] * dv[0][0] + cf[t * 4 + 1] * dv[1][0]
                + cf[t * 4 + 2] * dv[2][0] + cf[t * 4 + 3] * dv[3][0];
            o.y = cf[t * 4 + 0] * dv[0][1] + cf[t * 4 + 1] * dv[1][1]
                + cf[t * 4 + 2] * dv[2][1] + cf[t * 4 + 3] * dv[3][1];
            o.z = cf[t * 4 + 0] * dv[0][2] + cf[t * 4 + 1] * dv[1][2]
                + cf[t * 4 + 2] * dv[2][2] + cf[t * 4 + 3] * dv[3][2];
            o.w = cf[t * 4 + 0] * dv[0][3] + cf[t * 4 + 1] * dv[1][3]
                + cf[t * 4 + 2] * dv[2][3] + cf[t * 4 + 3] * dv[3][3];
            __builtin_nontemporal_store(o, (f32x4*)(ob + (size_t)t * NN * DD + d0));
        }
    }
}

extern "C" void kernel_launch(void* const* d_in, const int* in_sizes, int n_in,
                              void* d_out, int out_size, void* d_ws, size_t ws_size,
                              hipStream_t stream) {
    const float* residuals = (const float*)d_in[0];
    const float* gamma     = (const float*)d_in[1];
    const float* daf       = (const float*)d_in[2];
    const float* sa        = (const float*)d_in[3];
    const float* pbs       = (const float*)d_in[4];
    const float* rsc       = (const float*)d_in[5];
    const float* dbf       = (const float*)d_in[6];
    const float* sb        = (const float*)d_in[7];
    const float* hps       = (const float*)d_in[8];
    float* out = (float*)d_out;

    __hip_bfloat16* Wbf = (__hip_bfloat16*)d_ws;    // 24*8192 bf16 = 384 KiB

    k0_prep<<<768, 256, 0, stream>>>(gamma, daf, dbf, Wbf);
    kf<<<NROWS / 4, 512, 0, stream>>>(residuals, Wbf, sa, sb, pbs, rsc, hps, out);
}

// Round 9
// 1823.178 us; speedup vs baseline: 1.6023x; 1.6023x over previous
//
#include <hip/hip_runtime.h>
#include <hip/hip_bf16.h>

typedef float f32x4 __attribute__((ext_vector_type(4)));
typedef unsigned int u32;
typedef u32 u32x2 __attribute__((ext_vector_type(2)));
typedef u32 u32x4 __attribute__((ext_vector_type(4)));

#define SD 8192      // S*D
#define NROWS 8192   // B*N
#define NN 4096      // N
#define DD 2048      // D

__device__ __forceinline__ u32 bfr(float f) {   // f32 -> bf16 bits, RNE
    u32 u = __float_as_uint(f);
    return (u + 0x7fffu + ((u >> 16) & 1u)) >> 16;
}
__device__ __forceinline__ float blo(u32 u) { return __uint_as_float(u << 16); }
__device__ __forceinline__ float bhi(u32 u) { return __uint_as_float(u & 0xffff0000u); }

// K0: Wbf[k][j] = bf16( w[j][k] * (gamma[j]+1) ), k 0..23 (20 alpha, 4 beta)
__global__ void k0_prep(const float* __restrict__ gamma,
                        const float* __restrict__ daf,
                        const float* __restrict__ dbf,
                        __hip_bfloat16* __restrict__ Wbf) {
    int idx = blockIdx.x * 256 + threadIdx.x;
    if (idx >= 24 * SD) return;
    int k = idx >> 13;
    int j = idx & (SD - 1);
    float g = gamma[j] + 1.0f;
    float w = (k < 20) ? daf[j * 20 + k] : dbf[j * 4 + (k - 20)];
    ((unsigned short*)Wbf)[(size_t)k * SD + j] = (unsigned short)bfr(w * g);
}

// KF: fused. Block = 4 (b,n)-rows, 512 threads (8 waves). NO forced occupancy
// minimum (launch_bounds min-waves>=4 clamps VGPR to 64 and spills -- R3/R8).
// P1: stage rows f32->reg (exact ssq) ->bf16 LDS (64 KiB), nontemporal loads.
// P2: projections: wave (kg=w>>1 owns 6 k, jg=w&1 owns j-half) from bf16 LDS
//     data x bf16 global weights (L2-resident, each element once per block).
// P3: wave 0: sinkhorn (20 it) + coeff for the 4 rows.
// P4: mix from bf16 LDS, nontemporal f32x4 stores.
__global__ __launch_bounds__(512) void kf(const float* __restrict__ res,
                                          const __hip_bfloat16* __restrict__ Wbf,
                                          const float* __restrict__ sa,
                                          const float* __restrict__ sb,
                                          const float* __restrict__ pbs,
                                          const float* __restrict__ rsc,
                                          const float* __restrict__ hps,
                                          float* __restrict__ out) {
    __shared__ u32 dT[4][4096];        // packed bf16x2; row r, pair jp (j=2*jp); 64 KiB
    __shared__ float ssqw[8];
    __shared__ float rsum[2][4][24];   // [jg][row][k]
    __shared__ float coefS[4][16];

    const int tid  = threadIdx.x;
    const int wv   = tid >> 6;
    const int lane = tid & 63;
    const int row0 = blockIdx.x * 4;
    const int b    = row0 >> 12;
    const int n0   = row0 & (NN - 1);
    const int r    = tid >> 7;          // staging/mix row 0..3
    const int rem  = tid & 127;

    // ---------- P1: stage 4 rows, exact ssq, pack bf16 ----------
    const float* rowbase = res + ((size_t)(b * 4) * NN + (n0 + r)) * DD;
    float ssq = 0.f;
#pragma unroll
    for (int h = 0; h < 4; ++h) {
        f32x4 v[4];
#pragma unroll
        for (int i = 0; i < 4; ++i) {
            const int q  = h * 4 + i;
            const int j0 = (rem + 128 * q) * 4;
            const int s  = j0 >> 11, d = j0 & 2047;
            v[i] = __builtin_nontemporal_load((const f32x4*)(rowbase + (size_t)s * NN * DD + d));
        }
#pragma unroll
        for (int i = 0; i < 4; ++i) {
            ssq += v[i].x * v[i].x + v[i].y * v[i].y + v[i].z * v[i].z + v[i].w * v[i].w;
            u32 lo = (bfr(v[i].y) << 16) | bfr(v[i].x);
            u32 hi = (bfr(v[i].w) << 16) | bfr(v[i].z);
            const int jp = (rem + 128 * (h * 4 + i)) * 2;
            *(u32x2*)&dT[r][jp] = (u32x2){lo, hi};
        }
    }
    // wave covers a single row -> butterfly then one slot per wave
    ssq += __shfl_xor(ssq, 1);  ssq += __shfl_xor(ssq, 2);
    ssq += __shfl_xor(ssq, 4);  ssq += __shfl_xor(ssq, 8);
    ssq += __shfl_xor(ssq, 16); ssq += __shfl_xor(ssq, 32);
    if (lane == 0) ssqw[wv] = ssq;
    __syncthreads();

    // ---------- P2: projections ----------
    {
        const int kg = wv >> 1, jg = wv & 1;
        const int k0 = kg * 6;
        float acc[4][6];
#pragma unroll
        for (int rr = 0; rr < 4; ++rr)
#pragma unroll
            for (int kk = 0; kk < 6; ++kk) acc[rr][kk] = 0.f;

        const unsigned short* wb = (const unsigned short*)Wbf + (size_t)k0 * SD + jg * 4096 + lane * 8;
#pragma unroll
        for (int i = 0; i < 8; ++i) {
            const int jp0 = jg * 2048 + i * 256 + lane * 4;
            u32x4 dr[4];
#pragma unroll
            for (int rr = 0; rr < 4; ++rr) dr[rr] = *(const u32x4*)&dT[rr][jp0];
            float df[4][8];
#pragma unroll
            for (int rr = 0; rr < 4; ++rr)
#pragma unroll
                for (int p = 0; p < 4; ++p) {
                    df[rr][2 * p]     = blo(dr[rr][p]);
                    df[rr][2 * p + 1] = bhi(dr[rr][p]);
                }
#pragma unroll
            for (int kk = 0; kk < 6; ++kk) {
                const u32x4 wq = *(const u32x4*)(wb + (size_t)kk * SD + i * 512);
#pragma unroll
                for (int p = 0; p < 4; ++p) {
                    const float wlo = blo(wq[p]), whi = bhi(wq[p]);
#pragma unroll
                    for (int rr = 0; rr < 4; ++rr) {
                        acc[rr][kk] += df[rr][2 * p] * wlo;
                        acc[rr][kk] += df[rr][2 * p + 1] * whi;
                    }
                }
            }
        }
#pragma unroll
        for (int rr = 0; rr < 4; ++rr)
#pragma unroll
            for (int kk = 0; kk < 6; ++kk) {
                float v = acc[rr][kk];
                v += __shfl_xor(v, 1);  v += __shfl_xor(v, 2);
                v += __shfl_xor(v, 4);  v += __shfl_xor(v, 8);
                v += __shfl_xor(v, 16); v += __shfl_xor(v, 32);
                if (lane == 0) rsum[jg][rr][k0 + kk] = v;
            }
    }
    __syncthreads();

    // ---------- P3: sinkhorn + coeff (wave 0; 4 rows x 16 lanes) ----------
    if (wv == 0) {
        const int rr = lane >> 4, l = lane & 15, s = l >> 2, t = l & 3;
        const float ssqr  = ssqw[2 * rr] + ssqw[2 * rr + 1];
        const float scale = 90.50966799187809f / fmaxf(sqrtf(ssqr), 1e-12f);
        const float P  = rsum[0][rr][s * 5 + t + 1] + rsum[1][rr][s * 5 + t + 1];
        const float P0 = rsum[0][rr][s * 5]         + rsum[1][rr][s * 5];
        const float Pb = rsum[0][rr][20 + t]        + rsum[1][rr][20 + t];
        float la = scale * P * rsc[0] + sa[s * 5 + t + 1];
        const float a0 = scale * P0 * pbs[0] + sa[s * 5];
        const float ap = 1.f / (1.f + __expf(-a0));
        const float bt = 2.f / (1.f + __expf(-(scale * Pb * hps[0] + sb[t])));
#pragma unroll
        for (int it = 0; it < 20; ++it) {
            float m = fmaxf(la, __shfl_xor(la, 4));
            m = fmaxf(m, __shfl_xor(m, 8));
            float e = __expf(la - m);
            e += __shfl_xor(e, 4);
            e += __shfl_xor(e, 8);
            la -= m + __logf(e);
            m = fmaxf(la, __shfl_xor(la, 1));
            m = fmaxf(m, __shfl_xor(m, 2));
            e = __expf(la - m);
            e += __shfl_xor(e, 1);
            e += __shfl_xor(e, 2);
            la -= m + __logf(e);
        }
        coefS[rr][t * 4 + s] = ap * bt + __expf(la);
    }
    __syncthreads();

    // ---------- P4: mix + store ----------
    float cf[16];
#pragma unroll
    for (int i = 0; i < 16; ++i) cf[i] = coefS[r][i];
    float* ob = out + ((size_t)(b * 4) * NN + (n0 + r)) * DD;
#pragma unroll
    for (int qq = 0; qq < 4; ++qq) {
        const int d0 = (rem + 128 * qq) * 4;
        float dv[4][4];
#pragma unroll
        for (int s = 0; s < 4; ++s) {
            u32x2 u = *(const u32x2*)&dT[r][s * 1024 + d0 / 2];
            dv[s][0] = blo(u[0]); dv[s][1] = bhi(u[0]);
            dv[s][2] = blo(u[1]); dv[s][3] = bhi(u[1]);
        }
#pragma unroll
        for (int t = 0; t < 4; ++t) {
            f32x4 o;
            o.x = cf[t * 4 + 0] * dv[0][0] + cf[t * 4 + 1] * dv[1][0]
                + cf[t * 4 + 2] * dv[2][0] + cf[t * 4 + 3] * dv[3][0];
            o.y = cf[t * 4 + 0] * dv[0][1] + cf[t * 4 + 1] * dv[1][1]
                + cf[t * 4 + 2] * dv[2][1] + cf[t * 4 + 3] * dv[3][1];
            o.z = cf[t * 4 + 0] * dv[0][2] + cf[t * 4 + 1] * dv[1][2]
                + cf[t * 4 + 2] * dv[2][2] + cf[t * 4 + 3] * dv[3][2];
            o.w = cf[t * 4 + 0] * dv[0][3] + cf[t * 4 + 1] * dv[1][3]
                + cf[t * 4 + 2] * dv[2][3] + cf[t * 4 + 3] * dv[3][3];
            __builtin_nontemporal_store(o, (f32x4*)(ob + (size_t)t * NN * DD + d0));
        }
    }
}

extern "C" void kernel_launch(void* const* d_in, const int* in_sizes, int n_in,
                              void* d_out, int out_size, void* d_ws, size_t ws_size,
                              hipStream_t stream) {
    const float* residuals = (const float*)d_in[0];
    const float* gamma     = (const float*)d_in[1];
    const float* daf       = (const float*)d_in[2];
    const float* sa        = (const float*)d_in[3];
    const float* pbs       = (const float*)d_in[4];
    const float* rsc       = (const float*)d_in[5];
    const float* dbf       = (const float*)d_in[6];
    const float* sb        = (const float*)d_in[7];
    const float* hps       = (const float*)d_in[8];
    float* out = (float*)d_out;

    __hip_bfloat16* Wbf = (__hip_bfloat16*)d_ws;    // 24*8192 bf16 = 384 KiB

    k0_prep<<<768, 256, 0, stream>>>(gamma, daf, dbf, Wbf);
    kf<<<NROWS / 4, 512, 0, stream>>>(residuals, Wbf, sa, sb, pbs, rsc, hps, out);
}

// Round 10
// 1353.933 us; speedup vs baseline: 2.1576x; 1.3466x over previous
//
#include <hip/hip_runtime.h>
#include <hip/hip_bf16.h>

typedef float f32x4 __attribute__((ext_vector_type(4)));
typedef unsigned int u32;
typedef u32 u32x2 __attribute__((ext_vector_type(2)));
typedef u32 u32x4 __attribute__((ext_vector_type(4)));

#define SD 8192      // S*D
#define NROWS 8192   // B*N
#define NN 4096      // N
#define DD 2048      // D

__device__ __forceinline__ u32 bfr(float f) {   // f32 -> bf16 bits, RNE
    u32 u = __float_as_uint(f);
    return (u + 0x7fffu + ((u >> 16) & 1u)) >> 16;
}
__device__ __forceinline__ float blo(u32 u) { return __uint_as_float(u << 16); }
__device__ __forceinline__ float bhi(u32 u) { return __uint_as_float(u & 0xffff0000u); }

// K0: Wbf[k][j] = bf16( w[j][k] * (gamma[j]+1) ), k 0..23 (20 alpha, 4 beta)
__global__ void k0_prep(const float* __restrict__ gamma,
                        const float* __restrict__ daf,
                        const float* __restrict__ dbf,
                        __hip_bfloat16* __restrict__ Wbf) {
    int idx = blockIdx.x * 256 + threadIdx.x;
    if (idx >= 24 * SD) return;
    int k = idx >> 13;
    int j = idx & (SD - 1);
    float g = gamma[j] + 1.0f;
    float w = (k < 20) ? daf[j * 20 + k] : dbf[j * 4 + (k - 20)];
    ((unsigned short*)Wbf)[(size_t)k * SD + j] = (unsigned short)bfr(w * g);
}

// KF: fused. Block = 4 (b,n)-rows, 512 threads (8 waves), ~2 blocks/CU.
// Register discipline (R8/R9 lesson: 512-thr blocks get a ~128-VGPR target and
// SPILL rather than exceed it): every phase keeps live set < ~60 regs.
// P1: stage rows f32->reg (exact ssq) -> bf16 LDS (64 KiB), nontemporal loads.
// P2: projections in TWO row-passes (2 rows/pass): wave (kg=wv>>1 owns 6 k,
//     jg=wv&1 owns j-half); bf16 LDS data x bf16 global weights (L2-resident).
// P3: wave 0: sinkhorn (20 it) + coeff for the 4 rows.
// P4: mix from bf16 LDS, nontemporal f32x4 stores.
__global__ __launch_bounds__(512) void kf(const float* __restrict__ res,
                                          const __hip_bfloat16* __restrict__ Wbf,
                                          const float* __restrict__ sa,
                                          const float* __restrict__ sb,
                                          const float* __restrict__ pbs,
                                          const float* __restrict__ rsc,
                                          const float* __restrict__ hps,
                                          float* __restrict__ out) {
    __shared__ u32 dT[4][4096];        // packed bf16x2; row r, pair jp (j=2*jp); 64 KiB
    __shared__ float ssqw[8];
    __shared__ float rsum[2][4][24];   // [jg][row][k]
    __shared__ float coefS[4][16];

    const int tid  = threadIdx.x;
    const int wv   = tid >> 6;
    const int lane = tid & 63;
    const int row0 = blockIdx.x * 4;
    const int b    = row0 >> 12;
    const int n0   = row0 & (NN - 1);
    const int r    = tid >> 7;          // staging/mix row 0..3
    const int rem  = tid & 127;

    // ---------- P1: stage 4 rows, exact ssq, pack bf16 ----------
    const float* rowbase = res + ((size_t)(b * 4) * NN + (n0 + r)) * DD;
    float ssq = 0.f;
#pragma unroll
    for (int h = 0; h < 4; ++h) {
        f32x4 v[4];
#pragma unroll
        for (int i = 0; i < 4; ++i) {
            const int q  = h * 4 + i;
            const int j0 = (rem + 128 * q) * 4;
            const int s  = j0 >> 11, d = j0 & 2047;
            v[i] = __builtin_nontemporal_load((const f32x4*)(rowbase + (size_t)s * NN * DD + d));
        }
#pragma unroll
        for (int i = 0; i < 4; ++i) {
            ssq += v[i].x * v[i].x + v[i].y * v[i].y + v[i].z * v[i].z + v[i].w * v[i].w;
            u32 lo = (bfr(v[i].y) << 16) | bfr(v[i].x);
            u32 hi = (bfr(v[i].w) << 16) | bfr(v[i].z);
            const int jp = (rem + 128 * (h * 4 + i)) * 2;
            *(u32x2*)&dT[r][jp] = (u32x2){lo, hi};
        }
    }
    // wave covers a single row -> butterfly then one slot per wave
    ssq += __shfl_xor(ssq, 1);  ssq += __shfl_xor(ssq, 2);
    ssq += __shfl_xor(ssq, 4);  ssq += __shfl_xor(ssq, 8);
    ssq += __shfl_xor(ssq, 16); ssq += __shfl_xor(ssq, 32);
    if (lane == 0) ssqw[wv] = ssq;
    __syncthreads();

    // ---------- P2: projections, two row-passes of 2 rows ----------
    {
        const int kg = wv >> 1, jg = wv & 1;
        const int k0 = kg * 6;
        const unsigned short* wb = (const unsigned short*)Wbf + (size_t)k0 * SD + jg * 4096 + lane * 8;
#pragma unroll
        for (int half = 0; half < 2; ++half) {
            float acc[2][6];
#pragma unroll
            for (int rr = 0; rr < 2; ++rr)
#pragma unroll
                for (int kk = 0; kk < 6; ++kk) acc[rr][kk] = 0.f;

#pragma unroll
            for (int i = 0; i < 8; ++i) {
                const int jp0 = jg * 2048 + i * 256 + lane * 4;
                const u32x4 dr0 = *(const u32x4*)&dT[half * 2 + 0][jp0];
                const u32x4 dr1 = *(const u32x4*)&dT[half * 2 + 1][jp0];
                float df0[8], df1[8];
#pragma unroll
                for (int p = 0; p < 4; ++p) {
                    df0[2 * p] = blo(dr0[p]); df0[2 * p + 1] = bhi(dr0[p]);
                    df1[2 * p] = blo(dr1[p]); df1[2 * p + 1] = bhi(dr1[p]);
                }
#pragma unroll
                for (int kk = 0; kk < 6; ++kk) {
                    const u32x4 wq = *(const u32x4*)(wb + (size_t)kk * SD + i * 512);
#pragma unroll
                    for (int p = 0; p < 4; ++p) {
                        const float wlo = blo(wq[p]), whi = bhi(wq[p]);
                        acc[0][kk] += df0[2 * p] * wlo;
                        acc[0][kk] += df0[2 * p + 1] * whi;
                        acc[1][kk] += df1[2 * p] * wlo;
                        acc[1][kk] += df1[2 * p + 1] * whi;
                    }
                }
            }
#pragma unroll
            for (int rr = 0; rr < 2; ++rr)
#pragma unroll
                for (int kk = 0; kk < 6; ++kk) {
                    float v = acc[rr][kk];
                    v += __shfl_xor(v, 1);  v += __shfl_xor(v, 2);
                    v += __shfl_xor(v, 4);  v += __shfl_xor(v, 8);
                    v += __shfl_xor(v, 16); v += __shfl_xor(v, 32);
                    if (lane == 0) rsum[jg][half * 2 + rr][k0 + kk] = v;
                }
        }
    }
    __syncthreads();

    // ---------- P3: sinkhorn + coeff (wave 0; 4 rows x 16 lanes) ----------
    if (wv == 0) {
        const int rr = lane >> 4, l = lane & 15, s = l >> 2, t = l & 3;
        const float ssqr  = ssqw[2 * rr] + ssqw[2 * rr + 1];
        const float scale = 90.50966799187809f / fmaxf(sqrtf(ssqr), 1e-12f);
        const float P  = rsum[0][rr][s * 5 + t + 1] + rsum[1][rr][s * 5 + t + 1];
        const float P0 = rsum[0][rr][s * 5]         + rsum[1][rr][s * 5];
        const float Pb = rsum[0][rr][20 + t]        + rsum[1][rr][20 + t];
        float la = scale * P * rsc[0] + sa[s * 5 + t + 1];
        const float a0 = scale * P0 * pbs[0] + sa[s * 5];
        const float ap = 1.f / (1.f + __expf(-a0));
        const float bt = 2.f / (1.f + __expf(-(scale * Pb * hps[0] + sb[t])));
#pragma unroll
        for (int it = 0; it < 20; ++it) {
            float m = fmaxf(la, __shfl_xor(la, 4));
            m = fmaxf(m, __shfl_xor(m, 8));
            float e = __expf(la - m);
            e += __shfl_xor(e, 4);
            e += __shfl_xor(e, 8);
            la -= m + __logf(e);
            m = fmaxf(la, __shfl_xor(la, 1));
            m = fmaxf(m, __shfl_xor(m, 2));
            e = __expf(la - m);
            e += __shfl_xor(e, 1);
            e += __shfl_xor(e, 2);
            la -= m + __logf(e);
        }
        coefS[rr][t * 4 + s] = ap * bt + __expf(la);
    }
    __syncthreads();

    // ---------- P4: mix + store ----------
    float cf[16];
#pragma unroll
    for (int i = 0; i < 16; ++i) cf[i] = coefS[r][i];
    float* ob = out + ((size_t)(b * 4) * NN + (n0 + r)) * DD;
#pragma unroll
    for (int qq = 0; qq < 4; ++qq) {
        const int d0 = (rem + 128 * qq) * 4;
        float dv[4][4];
#pragma unroll
        for (int s = 0; s < 4; ++s) {
            u32x2 u = *(const u32x2*)&dT[r][s * 1024 + d0 / 2];
            dv[s][0] = blo(u[0]); dv[s][1] = bhi(u[0]);
            dv[s][2] = blo(u[1]); dv[s][3] = bhi(u[1]);
        }
#pragma unroll
        for (int t = 0; t < 4; ++t) {
            f32x4 o;
            o.x = cf[t * 4 + 0] * dv[0][0] + cf[t * 4 + 1] * dv[1][0]
                + cf[t * 4 + 2] * dv[2][0] + cf[t * 4 + 3] * dv[3][0];
            o.y = cf[t * 4 + 0] * dv[0][1] + cf[t * 4 + 1] * dv[1][1]
                + cf[t * 4 + 2] * dv[2][1] + cf[t * 4 + 3] * dv[3][1];
            o.z = cf[t * 4 + 0] * dv[0][2] + cf[t * 4 + 1] * dv[1][2]
                + cf[t * 4 + 2] * dv[2][2] + cf[t * 4 + 3] * dv[3][2];
            o.w = cf[t * 4 + 0] * dv[0][3] + cf[t * 4 + 1] * dv[1][3]
                + cf[t * 4 + 2] * dv[2][3] + cf[t * 4 + 3] * dv[3][3];
            __builtin_nontemporal_store(o, (f32x4*)(ob + (size_t)t * NN * DD + d0));
        }
    }
}

extern "C" void kernel_launch(void* const* d_in, const int* in_sizes, int n_in,
                              void* d_out, int out_size, void* d_ws, size_t ws_size,
                              hipStream_t stream) {
    const float* residuals = (const float*)d_in[0];
    const float* gamma     = (const float*)d_in[1];
    const float* daf       = (const float*)d_in[2];
    const float* sa        = (const float*)d_in[3];
    const float* pbs       = (const float*)d_in[4];
    const float* rsc       = (const float*)d_in[5];
    const float* dbf       = (const float*)d_in[6];
    const float* sb        = (const float*)d_in[7];
    const float* hps       = (const float*)d_in[8];
    float* out = (float*)d_out;

    __hip_bfloat16* Wbf = (__hip_bfloat16*)d_ws;    // 24*8192 bf16 = 384 KiB

    k0_prep<<<768, 256, 0, stream>>>(gamma, daf, dbf, Wbf);
    kf<<<NROWS / 4, 512, 0, stream>>>(residuals, Wbf, sa, sb, pbs, rsc, hps, out);
}

// Round 11
// 177.460 us; speedup vs baseline: 16.4615x; 7.6295x over previous
//
#include <hip/hip_runtime.h>
#include <hip/hip_bf16.h>

typedef float f32x4 __attribute__((ext_vector_type(4)));
typedef unsigned int u32;
typedef u32 u32x2 __attribute__((ext_vector_type(2)));
typedef u32 u32x4 __attribute__((ext_vector_type(4)));

#define SD 8192      // S*D
#define NROWS 8192   // B*N
#define NN 4096      // N
#define DD 2048      // D

__device__ __forceinline__ u32 bfr(float f) {   // f32 -> bf16 bits, RNE
    u32 u = __float_as_uint(f);
    return (u + 0x7fffu + ((u >> 16) & 1u)) >> 16;
}
__device__ __forceinline__ float blo(u32 u) { return __uint_as_float(u << 16); }
__device__ __forceinline__ float bhi(u32 u) { return __uint_as_float(u & 0xffff0000u); }

// K0: Wbf[k][j] = bf16( w[j][k] * (gamma[j]+1) ), k 0..23 (20 alpha, 4 beta)
__global__ void k0_prep(const float* __restrict__ gamma,
                        const float* __restrict__ daf,
                        const float* __restrict__ dbf,
                        __hip_bfloat16* __restrict__ Wbf) {
    int idx = blockIdx.x * 256 + threadIdx.x;
    if (idx >= 24 * SD) return;
    int k = idx >> 13;
    int j = idx & (SD - 1);
    float g = gamma[j] + 1.0f;
    float w = (k < 20) ? daf[j * 20 + k] : dbf[j * 4 + (k - 20)];
    ((unsigned short*)Wbf)[(size_t)k * SD + j] = (unsigned short)bfr(w * g);
}

// KF: fused, spill-proof. Block = 4 rows, 512 threads (8 waves).
// KEY (R8-R10 lesson): every load-carrying loop is ROLLED (#pragma unroll 1).
// Fully-unrolled load loops let the scheduler hoist ALL loads (~190 regs),
// which spills ~1.7 GB to scratch. Rolled loops cap live regs at ~70; latency
// is hidden by TLP (2 blocks/CU x 8 waves), not single-wave MLP.
// P1: stage rows f32->reg->bf16 LDS (64 KiB), exact ssq, nontemporal loads.
// P2: projections; wave (kg=wv>>1: 6 k's, jg=wv&1: j-half); bf16 LDS data x
//     bf16 global weights (L2-resident; 384 KiB/block re-read).
// P3: wave 0: 20-iter sinkhorn + coeff.  P4: mix from LDS, nt stores.
__global__ __launch_bounds__(512) void kf(const float* __restrict__ res,
                                          const __hip_bfloat16* __restrict__ Wbf,
                                          const float* __restrict__ sa,
                                          const float* __restrict__ sb,
                                          const float* __restrict__ pbs,
                                          const float* __restrict__ rsc,
                                          const float* __restrict__ hps,
                                          float* __restrict__ out) {
    __shared__ u32 dT[4][4096];        // packed bf16x2; row r, pair jp (j=2*jp); 64 KiB
    __shared__ float ssqw[8];
    __shared__ float rsum[2][4][24];   // [jg][row][k]
    __shared__ float coefS[4][16];

    const int tid  = threadIdx.x;
    const int wv   = tid >> 6;
    const int lane = tid & 63;
    const int row0 = blockIdx.x * 4;
    const int b    = row0 >> 12;
    const int n0   = row0 & (NN - 1);
    const int r    = tid >> 7;          // staging/mix row 0..3
    const int rem  = tid & 127;

    // ---------- P1: stage 4 rows, exact ssq, pack bf16 ----------
    const float* rowbase = res + ((size_t)(b * 4) * NN + (n0 + r)) * DD;
    float ssq = 0.f;
#pragma unroll 1
    for (int h = 0; h < 4; ++h) {
        f32x4 v[4];
#pragma unroll
        for (int i = 0; i < 4; ++i) {
            const int q  = h * 4 + i;
            const int j0 = (rem + 128 * q) * 4;
            const int s  = j0 >> 11, d = j0 & 2047;
            v[i] = __builtin_nontemporal_load((const f32x4*)(rowbase + (size_t)s * NN * DD + d));
        }
#pragma unroll
        for (int i = 0; i < 4; ++i) {
            ssq += v[i].x * v[i].x + v[i].y * v[i].y + v[i].z * v[i].z + v[i].w * v[i].w;
            u32 lo = (bfr(v[i].y) << 16) | bfr(v[i].x);
            u32 hi = (bfr(v[i].w) << 16) | bfr(v[i].z);
            const int jp = (rem + 128 * (h * 4 + i)) * 2;
            *(u32x2*)&dT[r][jp] = (u32x2){lo, hi};
        }
    }
    ssq += __shfl_xor(ssq, 1);  ssq += __shfl_xor(ssq, 2);
    ssq += __shfl_xor(ssq, 4);  ssq += __shfl_xor(ssq, 8);
    ssq += __shfl_xor(ssq, 16); ssq += __shfl_xor(ssq, 32);
    if (lane == 0) ssqw[wv] = ssq;
    __syncthreads();

    // ---------- P2: projections (rolled loops, ~60 live regs) ----------
    {
        const int kg = wv >> 1, jg = wv & 1;
        const int k0 = kg * 6;
        const unsigned short* wb = (const unsigned short*)Wbf + (size_t)k0 * SD + jg * 4096 + lane * 8;
#pragma unroll 1
        for (int half = 0; half < 2; ++half) {
            float a0[6], a1[6];
#pragma unroll
            for (int kk = 0; kk < 6; ++kk) { a0[kk] = 0.f; a1[kk] = 0.f; }
#pragma unroll 1
            for (int i = 0; i < 8; ++i) {
                const int jp0 = jg * 2048 + i * 256 + lane * 4;
                const u32x4 d0 = *(const u32x4*)&dT[half * 2 + 0][jp0];
                const u32x4 d1 = *(const u32x4*)&dT[half * 2 + 1][jp0];
                float f0[8], f1[8];
#pragma unroll
                for (int p = 0; p < 4; ++p) {
                    f0[2 * p] = blo(d0[p]); f0[2 * p + 1] = bhi(d0[p]);
                    f1[2 * p] = blo(d1[p]); f1[2 * p + 1] = bhi(d1[p]);
                }
#pragma unroll
                for (int kk = 0; kk < 6; ++kk) {
                    const u32x4 wq = *(const u32x4*)(wb + (size_t)kk * SD + i * 512);
#pragma unroll
                    for (int p = 0; p < 4; ++p) {
                        const float wlo = blo(wq[p]), whi = bhi(wq[p]);
                        a0[kk] += f0[2 * p] * wlo;
                        a0[kk] += f0[2 * p + 1] * whi;
                        a1[kk] += f1[2 * p] * wlo;
                        a1[kk] += f1[2 * p + 1] * whi;
                    }
                }
            }
#pragma unroll
            for (int kk = 0; kk < 6; ++kk) {
                float v = a0[kk];
                v += __shfl_xor(v, 1);  v += __shfl_xor(v, 2);
                v += __shfl_xor(v, 4);  v += __shfl_xor(v, 8);
                v += __shfl_xor(v, 16); v += __shfl_xor(v, 32);
                if (lane == 0) rsum[jg][half * 2 + 0][k0 + kk] = v;
                float u = a1[kk];
                u += __shfl_xor(u, 1);  u += __shfl_xor(u, 2);
                u += __shfl_xor(u, 4);  u += __shfl_xor(u, 8);
                u += __shfl_xor(u, 16); u += __shfl_xor(u, 32);
                if (lane == 0) rsum[jg][half * 2 + 1][k0 + kk] = u;
            }
        }
    }
    __syncthreads();

    // ---------- P3: sinkhorn + coeff (wave 0; 4 rows x 16 lanes) ----------
    if (wv == 0) {
        const int rr = lane >> 4, l = lane & 15, s = l >> 2, t = l & 3;
        const float ssqr  = ssqw[2 * rr] + ssqw[2 * rr + 1];
        const float scale = 90.50966799187809f / fmaxf(sqrtf(ssqr), 1e-12f);
        const float P  = rsum[0][rr][s * 5 + t + 1] + rsum[1][rr][s * 5 + t + 1];
        const float P0 = rsum[0][rr][s * 5]         + rsum[1][rr][s * 5];
        const float Pb = rsum[0][rr][20 + t]        + rsum[1][rr][20 + t];
        float la = scale * P * rsc[0] + sa[s * 5 + t + 1];
        const float a0 = scale * P0 * pbs[0] + sa[s * 5];
        const float ap = 1.f / (1.f + __expf(-a0));
        const float bt = 2.f / (1.f + __expf(-(scale * Pb * hps[0] + sb[t])));
#pragma unroll
        for (int it = 0; it < 20; ++it) {
            float m = fmaxf(la, __shfl_xor(la, 4));
            m = fmaxf(m, __shfl_xor(m, 8));
            float e = __expf(la - m);
            e += __shfl_xor(e, 4);
            e += __shfl_xor(e, 8);
            la -= m + __logf(e);
            m = fmaxf(la, __shfl_xor(la, 1));
            m = fmaxf(m, __shfl_xor(m, 2));
            e = __expf(la - m);
            e += __shfl_xor(e, 1);
            e += __shfl_xor(e, 2);
            la -= m + __logf(e);
        }
        coefS[rr][t * 4 + s] = ap * bt + __expf(la);
    }
    __syncthreads();

    // ---------- P4: mix + store (rolled) ----------
    float cf[16];
#pragma unroll
    for (int i = 0; i < 16; ++i) cf[i] = coefS[r][i];
    float* ob = out + ((size_t)(b * 4) * NN + (n0 + r)) * DD;
#pragma unroll 1
    for (int qq = 0; qq < 4; ++qq) {
        const int d0 = (rem + 128 * qq) * 4;
        float dv[4][4];
#pragma unroll
        for (int s = 0; s < 4; ++s) {
            u32x2 u = *(const u32x2*)&dT[r][s * 1024 + d0 / 2];
            dv[s][0] = blo(u[0]); dv[s][1] = bhi(u[0]);
            dv[s][2] = blo(u[1]); dv[s][3] = bhi(u[1]);
        }
#pragma unroll
        for (int t = 0; t < 4; ++t) {
            f32x4 o;
            o.x = cf[t * 4 + 0] * dv[0][0] + cf[t * 4 + 1] * dv[1][0]
                + cf[t * 4 + 2] * dv[2][0] + cf[t * 4 + 3] * dv[3][0];
            o.y = cf[t * 4 + 0] * dv[0][1] + cf[t * 4 + 1] * dv[1][1]
                + cf[t * 4 + 2] * dv[2][1] + cf[t * 4 + 3] * dv[3][1];
            o.z = cf[t * 4 + 0] * dv[0][2] + cf[t * 4 + 1] * dv[1][2]
                + cf[t * 4 + 2] * dv[2][2] + cf[t * 4 + 3] * dv[3][2];
            o.w = cf[t * 4 + 0] * dv[0][3] + cf[t * 4 + 1] * dv[1][3]
                + cf[t * 4 + 2] * dv[2][3] + cf[t * 4 + 3] * dv[3][3];
            __builtin_nontemporal_store(o, (f32x4*)(ob + (size_t)t * NN * DD + d0));
        }
    }
}

extern "C" void kernel_launch(void* const* d_in, const int* in_sizes, int n_in,
                              void* d_out, int out_size, void* d_ws, size_t ws_size,
                              hipStream_t stream) {
    const float* residuals = (const float*)d_in[0];
    const float* gamma     = (const float*)d_in[1];
    const float* daf       = (const float*)d_in[2];
    const float* sa        = (const float*)d_in[3];
    const float* pbs       = (const float*)d_in[4];
    const float* rsc       = (const float*)d_in[5];
    const float* dbf       = (const float*)d_in[6];
    const float* sb        = (const float*)d_in[7];
    const float* hps       = (const float*)d_in[8];
    float* out = (float*)d_out;

    __hip_bfloat16* Wbf = (__hip_bfloat16*)d_ws;    // 24*8192 bf16 = 384 KiB

    k0_prep<<<768, 256, 0, stream>>>(gamma, daf, dbf, Wbf);
    kf<<<NROWS / 4, 512, 0, stream>>>(residuals, Wbf, sa, sb, pbs, rsc, hps, out);
}